// Round 1
// baseline (635.011 us; speedup 1.0000x reference)
//
#include <hip/hip_runtime.h>
#include <cstdint>
#include <cstddef>

#define F_IN 256
#define F_OUT 128
#define NEG_SLOPE 0.2f

// ---------------- GEMM: h = x @ W (fp32, 64x128 tile, BK=32) ----------------
#define BM 64
#define BK 32

__global__ __launch_bounds__(256) void gemm_kernel(const float* __restrict__ x,
                                                   const float* __restrict__ W,
                                                   float* __restrict__ h, int N) {
  __shared__ float xs[BK][BM + 4];   // transposed x tile; row stride 68 floats = 272B (16B aligned)
  __shared__ float ws[BK][F_OUT];
  const int tid = threadIdx.x;
  const int tx = tid & 15;   // 16 col groups of 8 cols
  const int ty = tid >> 4;   // 16 row groups of 4 rows
  const int m0 = blockIdx.x * BM;

  float acc[4][8];
#pragma unroll
  for (int r = 0; r < 4; ++r)
#pragma unroll
    for (int c = 0; c < 8; ++c) acc[r][c] = 0.f;

  for (int k0 = 0; k0 < F_IN; k0 += BK) {
    // stage x tile (store transposed): 64 rows x 32 k
#pragma unroll
    for (int it = 0; it < 2; ++it) {
      int idx = tid + it * 256;
      int row = idx >> 3;          // 0..63
      int c4  = (idx & 7) * 4;     // 0..28
      int gm = m0 + row;
      float4 v = make_float4(0.f, 0.f, 0.f, 0.f);
      if (gm < N) v = *(const float4*)(x + (size_t)gm * F_IN + k0 + c4);
      xs[c4 + 0][row] = v.x;
      xs[c4 + 1][row] = v.y;
      xs[c4 + 2][row] = v.z;
      xs[c4 + 3][row] = v.w;
    }
    // stage W tile: 32 k x 128
#pragma unroll
    for (int it = 0; it < 4; ++it) {
      int idx = tid + it * 256;
      int row = idx >> 5;          // 0..31
      int c4  = (idx & 31) * 4;    // 0..124
      *(float4*)&ws[row][c4] = *(const float4*)(W + (size_t)(k0 + row) * F_OUT + c4);
    }
    __syncthreads();

#pragma unroll
    for (int kk = 0; kk < BK; ++kk) {
      float4 xv = *(const float4*)&xs[kk][ty * 4];
      float4 wa = *(const float4*)&ws[kk][tx * 8];
      float4 wb = *(const float4*)&ws[kk][tx * 8 + 4];
      float xr[4] = {xv.x, xv.y, xv.z, xv.w};
      float wc[8] = {wa.x, wa.y, wa.z, wa.w, wb.x, wb.y, wb.z, wb.w};
#pragma unroll
      for (int r = 0; r < 4; ++r)
#pragma unroll
        for (int c = 0; c < 8; ++c)
          acc[r][c] += xr[r] * wc[c];
    }
    __syncthreads();
  }

#pragma unroll
  for (int r = 0; r < 4; ++r) {
    int gm = m0 + ty * 4 + r;
    if (gm < N) {
      float4 va = {acc[r][0], acc[r][1], acc[r][2], acc[r][3]};
      float4 vb = {acc[r][4], acc[r][5], acc[r][6], acc[r][7]};
      *(float4*)&h[(size_t)gm * F_OUT + tx * 8]     = va;
      *(float4*)&h[(size_t)gm * F_OUT + tx * 8 + 4] = vb;
    }
  }
}

// ---------------- per-node logits: a_src[i] = h[i,:]·att_src, a_dst likewise ----------------
__global__ __launch_bounds__(256) void logits_kernel(const float* __restrict__ h,
                                                     const float* __restrict__ att_src,
                                                     const float* __restrict__ att_dst,
                                                     float* __restrict__ a_src,
                                                     float* __restrict__ a_dst, int N) {
  int gtid = blockIdx.x * blockDim.x + threadIdx.x;
  int wid = gtid >> 6;        // one wave per node
  int lane = threadIdx.x & 63;
  if (wid >= N) return;
  const float* row = h + (size_t)wid * F_OUT;
  float h0 = row[lane], h1 = row[lane + 64];
  float ps = h0 * att_src[lane] + h1 * att_src[lane + 64];
  float pd = h0 * att_dst[lane] + h1 * att_dst[lane + 64];
#pragma unroll
  for (int off = 32; off > 0; off >>= 1) {
    ps += __shfl_down(ps, off, 64);
    pd += __shfl_down(pd, off, 64);
  }
  if (lane == 0) { a_src[wid] = ps; a_dst[wid] = pd; }
}

// ---------------- CSR build ----------------
__global__ void deg_init_kernel(int* __restrict__ deg, int N) {
  int i = blockIdx.x * blockDim.x + threadIdx.x;
  if (i < N) deg[i] = 1;  // self loop
}

__global__ void deg_count_kernel(const int* __restrict__ ei, int* __restrict__ deg, int E) {
  int e = blockIdx.x * blockDim.x + threadIdx.x;
  if (e < E) atomicAdd(&deg[ei[E + e]], 1);  // row 1 = dst
}

__global__ __launch_bounds__(1024) void scan_kernel(const int* __restrict__ deg,
                                                    int* __restrict__ rowptr,
                                                    int* __restrict__ cursor, int N) {
  __shared__ int wsum[16];
  __shared__ int carry;
  const int tid = threadIdx.x;
  const int lane = tid & 63;
  const int wid = tid >> 6;
  if (tid == 0) { carry = 0; rowptr[0] = 0; }
  __syncthreads();
  for (int base = 0; base < N; base += 1024) {
    int i = base + tid;
    int v = (i < N) ? deg[i] : 0;
    // wave-level inclusive scan
    int incl = v;
#pragma unroll
    for (int off = 1; off < 64; off <<= 1) {
      int t = __shfl_up(incl, off, 64);
      if (lane >= off) incl += t;
    }
    if (lane == 63) wsum[wid] = incl;
    __syncthreads();
    if (wid == 0) {
      int s = (lane < 16) ? wsum[lane] : 0;
#pragma unroll
      for (int off = 1; off < 16; off <<= 1) {
        int t = __shfl_up(s, off, 64);
        if (lane >= off) s += t;
      }
      if (lane < 16) wsum[lane] = s;
    }
    __syncthreads();
    int woff = (wid == 0) ? 0 : wsum[wid - 1];
    int inclt = incl + woff;
    if (i < N) {
      rowptr[i + 1] = carry + inclt;
      cursor[i] = carry + inclt - v;
    }
    __syncthreads();
    if (tid == 0) carry += wsum[15];
    __syncthreads();
  }
}

__global__ void scatter_kernel(const int* __restrict__ ei, int* __restrict__ cursor,
                               int* __restrict__ csr_src, int E, int N) {
  int idx = blockIdx.x * blockDim.x + threadIdx.x;
  if (idx >= E + N) return;
  int s, d;
  if (idx < E) { s = ei[idx]; d = ei[E + idx]; }
  else { s = d = idx - E; }
  int p = atomicAdd(&cursor[d], 1);
  csr_src[p] = s;
}

// ---------------- per-node softmax + aggregate (no atomics) ----------------
__global__ __launch_bounds__(256) void aggregate_kernel(const float* __restrict__ h,
                                                        const float* __restrict__ a_src,
                                                        const float* __restrict__ a_dst,
                                                        const int* __restrict__ rowptr,
                                                        const int* __restrict__ csr_src,
                                                        const float* __restrict__ bias,
                                                        float* __restrict__ out, int N) {
  int node = blockIdx.x * 2 + (threadIdx.x >> 7);   // 2 nodes per 256-thread block
  if (node >= N) return;
  int f = threadIdx.x & 127;
  int beg = rowptr[node], end = rowptr[node + 1];
  float ad = a_dst[node];

  float m = -INFINITY;
  for (int j = beg; j < end; ++j) {
    float e = a_src[csr_src[j]] + ad;
    e = (e > 0.f) ? e : NEG_SLOPE * e;
    m = fmaxf(m, e);
  }
  float s = 0.f;
  for (int j = beg; j < end; ++j) {
    float e = a_src[csr_src[j]] + ad;
    e = (e > 0.f) ? e : NEG_SLOPE * e;
    s += __expf(e - m);
  }
  float inv = 1.f / (s + 1e-16f);
  float acc = 0.f;
  for (int j = beg; j < end; ++j) {
    int sidx = csr_src[j];
    float e = a_src[sidx] + ad;
    e = (e > 0.f) ? e : NEG_SLOPE * e;
    float alpha = __expf(e - m) * inv;
    acc += alpha * h[(size_t)sidx * F_OUT + f];
  }
  out[(size_t)node * F_OUT + f] = acc + bias[f];
}

// ---------------- launch ----------------
extern "C" void kernel_launch(void* const* d_in, const int* in_sizes, int n_in,
                              void* d_out, int out_size, void* d_ws, size_t ws_size,
                              hipStream_t stream) {
  const float* x     = (const float*)d_in[0];
  const int*   ei    = (const int*)d_in[1];
  const float* W     = (const float*)d_in[2];
  const float* att_s = (const float*)d_in[3];
  const float* att_d = (const float*)d_in[4];
  const float* bias  = (const float*)d_in[5];
  float* out = (float*)d_out;

  const int N = in_sizes[0] / F_IN;
  const int E = in_sizes[1] / 2;

  char* p = (char*)d_ws;
  float* h     = (float*)p;  p += (size_t)N * F_OUT * sizeof(float);
  float* a_src = (float*)p;  p += (size_t)N * sizeof(float);
  float* a_dst = (float*)p;  p += (size_t)N * sizeof(float);
  int*   deg   = (int*)p;    p += (size_t)N * sizeof(int);
  int*   rowp  = (int*)p;    p += (size_t)(N + 1) * sizeof(int);
  int*   curs  = (int*)p;    p += (size_t)N * sizeof(int);
  int*   csr   = (int*)p;    p += (size_t)(E + N) * sizeof(int);

  gemm_kernel<<<(N + BM - 1) / BM, 256, 0, stream>>>(x, W, h, N);
  logits_kernel<<<((size_t)N * 64 + 255) / 256, 256, 0, stream>>>(h, att_s, att_d, a_src, a_dst, N);
  deg_init_kernel<<<(N + 255) / 256, 256, 0, stream>>>(deg, N);
  deg_count_kernel<<<(E + 255) / 256, 256, 0, stream>>>(ei, deg, E);
  scan_kernel<<<1, 1024, 0, stream>>>(deg, rowp, curs, N);
  scatter_kernel<<<(E + N + 255) / 256, 256, 0, stream>>>(ei, curs, csr, E, N);
  aggregate_kernel<<<(N + 1) / 2, 256, 0, stream>>>(h, a_src, a_dst, rowp, csr, bias, out, N);
}

// Round 2
// 355.297 us; speedup vs baseline: 1.7873x; 1.7873x over previous
//
#include <hip/hip_runtime.h>
#include <cstdint>
#include <cstddef>

#define F_IN 256
#define F_OUT 128
#define NEG_SLOPE 0.2f

// ---------------- GEMM: h = x @ W (fp32, 128x128 tile, BK=16) + fused logits ----------------
#define BM 128
#define BK 16

__global__ __launch_bounds__(256) void gemm_kernel(const float* __restrict__ x,
                                                   const float* __restrict__ W,
                                                   const float* __restrict__ att_src,
                                                   const float* __restrict__ att_dst,
                                                   float* __restrict__ h,
                                                   float* __restrict__ a_src,
                                                   float* __restrict__ a_dst, int N) {
  __shared__ float xs[BK][BM + 4];   // transposed x tile
  __shared__ float ws[BK][F_OUT];
  const int tid = threadIdx.x;
  const int tx = tid & 15;   // col group: cols tx*8 .. tx*8+7
  const int ty = tid >> 4;   // row group: rows ty*8 .. ty*8+7
  const int m0 = blockIdx.x * BM;

  float acc[8][8];
#pragma unroll
  for (int r = 0; r < 8; ++r)
#pragma unroll
    for (int c = 0; c < 8; ++c) acc[r][c] = 0.f;

  for (int k0 = 0; k0 < F_IN; k0 += BK) {
    // stage x tile (transposed): 128 rows x 16 k = 2048 floats; 2 float4/thread
#pragma unroll
    for (int it = 0; it < 2; ++it) {
      int idx = tid + it * 256;      // 0..511
      int row = idx >> 2;            // 0..127
      int c4  = (idx & 3) * 4;       // 0,4,8,12
      int gm = m0 + row;
      float4 v = make_float4(0.f, 0.f, 0.f, 0.f);
      if (gm < N) v = *(const float4*)(x + (size_t)gm * F_IN + k0 + c4);
      xs[c4 + 0][row] = v.x;
      xs[c4 + 1][row] = v.y;
      xs[c4 + 2][row] = v.z;
      xs[c4 + 3][row] = v.w;
    }
    // stage W tile: 16 k x 128 = 2048 floats
#pragma unroll
    for (int it = 0; it < 2; ++it) {
      int idx = tid + it * 256;
      int row = idx >> 5;            // 0..15
      int c4  = (idx & 31) * 4;      // 0..124
      *(float4*)&ws[row][c4] = *(const float4*)(W + (size_t)(k0 + row) * F_OUT + c4);
    }
    __syncthreads();

#pragma unroll
    for (int kk = 0; kk < BK; ++kk) {
      float4 xa = *(const float4*)&xs[kk][ty * 8];
      float4 xb = *(const float4*)&xs[kk][ty * 8 + 4];
      float4 wa = *(const float4*)&ws[kk][tx * 8];
      float4 wb = *(const float4*)&ws[kk][tx * 8 + 4];
      float xr[8] = {xa.x, xa.y, xa.z, xa.w, xb.x, xb.y, xb.z, xb.w};
      float wc[8] = {wa.x, wa.y, wa.z, wa.w, wb.x, wb.y, wb.z, wb.w};
#pragma unroll
      for (int r = 0; r < 8; ++r)
#pragma unroll
        for (int c = 0; c < 8; ++c)
          acc[r][c] += xr[r] * wc[c];
    }
    __syncthreads();
  }

  // epilogue: write h + fused per-row logits (dot with att vectors)
  float as[8], adv[8];
#pragma unroll
  for (int c = 0; c < 8; ++c) {
    as[c]  = att_src[tx * 8 + c];
    adv[c] = att_dst[tx * 8 + c];
  }
#pragma unroll
  for (int r = 0; r < 8; ++r) {
    int gm = m0 + ty * 8 + r;
    float ps = 0.f, pd = 0.f;
#pragma unroll
    for (int c = 0; c < 8; ++c) {
      ps += acc[r][c] * as[c];
      pd += acc[r][c] * adv[c];
    }
#pragma unroll
    for (int off = 8; off >= 1; off >>= 1) {
      ps += __shfl_down(ps, off, 16);
      pd += __shfl_down(pd, off, 16);
    }
    if (gm < N) {
      float4 va = {acc[r][0], acc[r][1], acc[r][2], acc[r][3]};
      float4 vb = {acc[r][4], acc[r][5], acc[r][6], acc[r][7]};
      *(float4*)&h[(size_t)gm * F_OUT + tx * 8]     = va;
      *(float4*)&h[(size_t)gm * F_OUT + tx * 8 + 4] = vb;
      if (tx == 0) { a_src[gm] = ps; a_dst[gm] = pd; }
    }
  }
}

// ---------------- CSR build ----------------
__global__ void deg_init_kernel(int* __restrict__ deg, int N) {
  int i = blockIdx.x * blockDim.x + threadIdx.x;
  if (i < N) deg[i] = 1;  // self loop
}

__global__ void deg_count_kernel(const int* __restrict__ ei, int* __restrict__ deg, int E) {
  int e = blockIdx.x * blockDim.x + threadIdx.x;
  if (e < E) atomicAdd(&deg[ei[E + e]], 1);  // row 1 = dst
}

#define SCAN_CHUNK 2048  // 256 threads x 8 elements

__global__ __launch_bounds__(256) void scan_chunk_kernel(const int* __restrict__ deg,
                                                         int* __restrict__ rowptr,
                                                         int* __restrict__ chunksum, int N) {
  __shared__ int wsum[4];
  const int tid = threadIdx.x, lane = tid & 63, wid = tid >> 6;
  const int base = blockIdx.x * SCAN_CHUNK + tid * 8;
  int v[8];
  int s = 0;
#pragma unroll
  for (int q = 0; q < 8; ++q) {
    int i = base + q;
    v[q] = (i < N) ? deg[i] : 0;
    s += v[q];
  }
  int incl = s;
#pragma unroll
  for (int off = 1; off < 64; off <<= 1) {
    int t = __shfl_up(incl, off, 64);
    if (lane >= off) incl += t;
  }
  if (lane == 63) wsum[wid] = incl;
  __syncthreads();
  int woff = 0;
#pragma unroll
  for (int w = 0; w < 4; ++w)
    if (w < wid) woff += wsum[w];
  int run = woff + incl - s;  // exclusive prefix of this thread's first element
#pragma unroll
  for (int q = 0; q < 8; ++q) {
    run += v[q];
    int i = base + q;
    if (i < N) rowptr[i + 1] = run;  // pre-offset, fixed up later
  }
  if (tid == 0) chunksum[blockIdx.x] = wsum[0] + wsum[1] + wsum[2] + wsum[3];
}

__global__ void scan_offsets_kernel(const int* __restrict__ chunksum,
                                    int* __restrict__ chunkoff, int NB) {
  if (threadIdx.x == 0 && blockIdx.x == 0) {
    int run = 0;
    for (int b = 0; b < NB; ++b) { chunkoff[b] = run; run += chunksum[b]; }
  }
}

__global__ void scan_fixup_kernel(const int* __restrict__ deg, int* __restrict__ rowptr,
                                  int* __restrict__ cursor, const int* __restrict__ chunkoff,
                                  int N) {
  int i = blockIdx.x * blockDim.x + threadIdx.x;
  if (i == 0) rowptr[0] = 0;
  if (i < N) {
    int r = rowptr[i + 1] + chunkoff[i / SCAN_CHUNK];
    rowptr[i + 1] = r;
    cursor[i] = r - deg[i];
  }
}

__global__ void scatter_kernel(const int* __restrict__ ei, int* __restrict__ cursor,
                               int* __restrict__ csr_src, int E, int N) {
  int idx = blockIdx.x * blockDim.x + threadIdx.x;
  if (idx >= E + N) return;
  int s, d;
  if (idx < E) { s = ei[idx]; d = ei[E + idx]; }
  else { s = d = idx - E; }
  int p = atomicAdd(&cursor[d], 1);
  csr_src[p] = s;
}

// ---------------- softmax stats: one wave per node ----------------
__global__ __launch_bounds__(256) void stats_kernel(const float* __restrict__ a_src,
                                                    const float* __restrict__ a_dst,
                                                    const int* __restrict__ rowptr,
                                                    const int* __restrict__ csr_src,
                                                    float* __restrict__ ew,
                                                    float* __restrict__ inv, int N) {
  int node = (blockIdx.x * 256 + threadIdx.x) >> 6;
  int lane = threadIdx.x & 63;
  if (node >= N) return;
  int beg = rowptr[node], end = rowptr[node + 1];
  float ad = a_dst[node];
  float m = -INFINITY;
  for (int j = beg + lane; j < end; j += 64) {
    float e = a_src[csr_src[j]] + ad;
    e = (e > 0.f) ? e : NEG_SLOPE * e;
    ew[j] = e;
    m = fmaxf(m, e);
  }
#pragma unroll
  for (int off = 32; off >= 1; off >>= 1) m = fmaxf(m, __shfl_xor(m, off, 64));
  float s = 0.f;
  for (int j = beg + lane; j < end; j += 64) {
    float p = __expf(ew[j] - m);
    ew[j] = p;
    s += p;
  }
#pragma unroll
  for (int off = 32; off >= 1; off >>= 1) s += __shfl_xor(s, off, 64);
  if (lane == 0) inv[node] = 1.f / (s + 1e-16f);
}

// ---------------- weighted aggregate: 128 threads per node, x4 unrolled gathers ----------------
__global__ __launch_bounds__(256) void aggregate_kernel(const float* __restrict__ h,
                                                        const float* __restrict__ ew,
                                                        const float* __restrict__ inv,
                                                        const int* __restrict__ rowptr,
                                                        const int* __restrict__ csr_src,
                                                        const float* __restrict__ bias,
                                                        float* __restrict__ out, int N) {
  int node = blockIdx.x * 2 + (threadIdx.x >> 7);
  if (node >= N) return;
  int f = threadIdx.x & 127;
  int beg = rowptr[node], end = rowptr[node + 1];
  float acc = 0.f;
  int j = beg;
  for (; j + 4 <= end; j += 4) {
    int s0 = csr_src[j], s1 = csr_src[j + 1], s2 = csr_src[j + 2], s3 = csr_src[j + 3];
    float w0 = ew[j], w1 = ew[j + 1], w2 = ew[j + 2], w3 = ew[j + 3];
    float h0 = h[(size_t)s0 * F_OUT + f];
    float h1 = h[(size_t)s1 * F_OUT + f];
    float h2 = h[(size_t)s2 * F_OUT + f];
    float h3 = h[(size_t)s3 * F_OUT + f];
    acc += w0 * h0 + w1 * h1 + w2 * h2 + w3 * h3;
  }
  for (; j < end; ++j) acc += ew[j] * h[(size_t)csr_src[j] * F_OUT + f];
  out[(size_t)node * F_OUT + f] = acc * inv[node] + bias[f];
}

// ---------------- launch ----------------
extern "C" void kernel_launch(void* const* d_in, const int* in_sizes, int n_in,
                              void* d_out, int out_size, void* d_ws, size_t ws_size,
                              hipStream_t stream) {
  const float* x     = (const float*)d_in[0];
  const int*   ei    = (const int*)d_in[1];
  const float* W     = (const float*)d_in[2];
  const float* att_s = (const float*)d_in[3];
  const float* att_d = (const float*)d_in[4];
  const float* bias  = (const float*)d_in[5];
  float* out = (float*)d_out;

  const int N = in_sizes[0] / F_IN;
  const int E = in_sizes[1] / 2;
  const int NB = (N + SCAN_CHUNK - 1) / SCAN_CHUNK;

  char* p = (char*)d_ws;
  float* h     = (float*)p;  p += (size_t)N * F_OUT * sizeof(float);
  float* a_src = (float*)p;  p += (size_t)N * sizeof(float);
  float* a_dst = (float*)p;  p += (size_t)N * sizeof(float);
  float* inv   = (float*)p;  p += (size_t)N * sizeof(float);
  int*   deg   = (int*)p;    p += (size_t)N * sizeof(int);
  int*   rowp  = (int*)p;    p += (size_t)(N + 1) * sizeof(int);
  int*   curs  = (int*)p;    p += (size_t)N * sizeof(int);
  int*   csum  = (int*)p;    p += (size_t)NB * sizeof(int);
  int*   coff  = (int*)p;    p += (size_t)NB * sizeof(int);
  int*   csr   = (int*)p;    p += (size_t)(E + N) * sizeof(int);
  float* ew    = (float*)p;  p += (size_t)(E + N) * sizeof(float);

  gemm_kernel<<<(N + BM - 1) / BM, 256, 0, stream>>>(x, W, att_s, att_d, h, a_src, a_dst, N);
  deg_init_kernel<<<(N + 255) / 256, 256, 0, stream>>>(deg, N);
  deg_count_kernel<<<(E + 255) / 256, 256, 0, stream>>>(ei, deg, E);
  scan_chunk_kernel<<<NB, 256, 0, stream>>>(deg, rowp, csum, N);
  scan_offsets_kernel<<<1, 64, 0, stream>>>(csum, coff, NB);
  scan_fixup_kernel<<<(N + 255) / 256, 256, 0, stream>>>(deg, rowp, curs, coff, N);
  scatter_kernel<<<(E + N + 255) / 256, 256, 0, stream>>>(ei, curs, csr, E, N);
  stats_kernel<<<((size_t)N * 64 + 255) / 256, 256, 0, stream>>>(a_src, a_dst, rowp, csr, ew, inv, N);
  aggregate_kernel<<<(N + 1) / 2, 256, 0, stream>>>(h, ew, inv, rowp, csr, bias, out, N);
}